// Round 18
// baseline (504.279 us; speedup 1.0000x reference)
//
#include <hip/hip_runtime.h>

// GNN: 2-layer edge-coloured conv on MI355X.
// Round 18: k_gemm1s barrier-free row-sweep. Block = 64 cols x full K=1152,
// B panel 144KB LDS staged once; 4 waves sweep 16-row chunks with 36 hoisted
// A-loads each (36KB in flight/wave -> HBM-saturating). Grid (4 cb, 64 rb).
// Everything else = round 17 (passed, 341us).

#define NN 50000
#define EE 800000
#define DD 128
#define HH 256
#define CC 8
#define K1 1152   // C*D + D

typedef unsigned short u16;
typedef __attribute__((ext_vector_type(8))) short s16x8;
typedef __attribute__((ext_vector_type(4))) float f32x4;

__device__ __forceinline__ float bf2f(short u) {
  return __uint_as_float(((unsigned)(u16)u) << 16);
}
__device__ __forceinline__ u16 f2bf(float f) {
  unsigned u = __float_as_uint(f);
  u = (u + 0x7FFFu + ((u >> 16) & 1u)) >> 16;   // RNE
  return (u16)u;
}

// ---------------- prep ----------------

__global__ void k_castx(const float* __restrict__ x, u16* __restrict__ xb) {
  int i = blockIdx.x * 256 + threadIdx.x;
  if (i < NN * DD) xb[i] = f2bf(x[i]);
}

// W1f fragment-major: idx = (((col16*36 + kk)*4 + kg)*16 + rs)*8 + e
__global__ void k_wt1f(const float* __restrict__ Wc1, const float* __restrict__ Ws1,
                       u16* __restrict__ W) {
  int i = blockIdx.x * 256 + threadIdx.x;
  if (i >= 294912) return;
  int e = i & 7;
  int t = i >> 3;
  int rs = t & 15; t >>= 4;
  int kg = t & 3;  t >>= 2;
  int kk = t % 36;
  int col16 = t / 36;
  int col = col16 * 16 + rs;
  int k = kk * 32 + kg * 8 + e;
  float v = (k < CC * DD) ? Wc1[(k >> 7) * (HH * DD) + col * DD + (k & 127)]
                          : Ws1[col * DD + (k - CC * DD)];
  W[i] = f2bf(v);
}

// W2f fragment-major: idx = (((col16*8 + kk)*4 + kg)*16 + rs)*8 + e
__global__ void k_wt2f(const float* __restrict__ Wc2, const float* __restrict__ Ws2,
                       u16* __restrict__ W) {
  int i = blockIdx.x * 256 + threadIdx.x;
  if (i >= 294912) return;
  int e = i & 7;
  int t = i >> 3;
  int rs = t & 15; t >>= 4;
  int kg = t & 3;  t >>= 2;
  int kk = t & 7;
  int col16 = t >> 3;
  int oc = col16 * 16 + rs;
  int c = oc >> 7, o = oc & 127;
  int k = kk * 32 + kg * 8 + e;
  float v = (c < CC) ? Wc2[c * (DD * HH) + o * HH + k] : Ws2[o * HH + k];
  W[i] = f2bf(v);
}

// ---------------- CSR build over seg = dst*8 + c ----------------

__global__ void k_hist(const int* __restrict__ ei, const int* __restrict__ ec,
                       int* __restrict__ counts) {
  int e = blockIdx.x * 256 + threadIdx.x;
  if (e < EE) {
    int dst = ei[EE + e];
    int c = ec[e];
    atomicAdd(&counts[dst * CC + c], 1);
  }
}

__global__ void k_offsets(const int* __restrict__ counts, int2* __restrict__ oc,
                          int* __restrict__ cursor, int* __restrict__ gcount) {
  __shared__ int lds[256];
  __shared__ int basesh;
  int tid = threadIdx.x;
  int i = blockIdx.x * 256 + tid;
  int c = (i < CC * NN) ? counts[i] : 0;
  lds[tid] = c;
  __syncthreads();
  int v = c;
  for (int s = 1; s < 256; s <<= 1) {
    int t = (tid >= s) ? lds[tid - s] : 0;
    __syncthreads();
    v += t;
    lds[tid] = v;
    __syncthreads();
  }
  if (tid == 255) basesh = atomicAdd(gcount, v);
  __syncthreads();
  int excl = basesh + v - c;
  if (i < CC * NN) {
    oc[i] = make_int2(excl, c);
    cursor[i] = excl;
  }
}

// slot value packs src and colour: sv = src*8 + c
__global__ void k_fill(const int* __restrict__ ei, const int* __restrict__ ec,
                       int* __restrict__ cursor, int* __restrict__ sv) {
  int e = blockIdx.x * 256 + threadIdx.x;
  if (e < EE) {
    int src = ei[e];
    int dst = ei[EE + e];
    int c = ec[e];
    int slot = atomicAdd(&cursor[dst * CC + c], 1);
    sv[slot] = src * 8 + c;
  }
}

// ---------------- layer 1: balanced pure gather ----------------

__global__ void __launch_bounds__(256) k_agg1(
    const u16* __restrict__ xb, const int2* __restrict__ oc,
    const int* __restrict__ sv, u16* __restrict__ agg) {
  int item = blockIdx.x * 256 + threadIdx.x;
  int dst = item >> 4, ch = item & 15;
  int eoff = ch * 8;
#pragma unroll
  for (int c = 0; c < CC; ++c) {
    int2 se = oc[dst * CC + c];
    float s[8];
#pragma unroll
    for (int q = 0; q < 8; q++) s[q] = 0.f;
    int j = 0;
    for (; j + 1 < se.y; j += 2) {
      int s0 = sv[se.x + j] >> 3;
      int s1 = sv[se.x + j + 1] >> 3;
      s16x8 v0 = *(const s16x8*)(xb + (size_t)s0 * DD + eoff);
      s16x8 v1 = *(const s16x8*)(xb + (size_t)s1 * DD + eoff);
#pragma unroll
      for (int q = 0; q < 8; q++) s[q] += bf2f(v0[q]) + bf2f(v1[q]);
    }
    if (j < se.y) {
      int s0 = sv[se.x + j] >> 3;
      s16x8 v0 = *(const s16x8*)(xb + (size_t)s0 * DD + eoff);
#pragma unroll
      for (int q = 0; q < 8; q++) s[q] += bf2f(v0[q]);
    }
    s16x8 r;
#pragma unroll
    for (int q = 0; q < 8; q++) r[q] = (short)f2bf(s[q]);
    *(s16x8*)(agg + ((size_t)c * NN + dst) * DD + eoff) = r;
  }
}

// ---------------- layer 1 dense: barrier-free sweep, full-K LDS B ----------
// Grid (4 cb, 64 rb). Block: 64 cols x K=1152 B panel (144KB) staged once;
// 4 waves sweep 16-row chunks (stride 64 rows) with 36 hoisted A-loads.

__global__ void __launch_bounds__(256, 1) k_gemm1s(
    const u16* __restrict__ xb, const u16* __restrict__ agg,
    const u16* __restrict__ Wf, const float* __restrict__ b1,
    u16* __restrict__ hb) {
  __shared__ u16 Bs[73728];               // 144KB: [fc 4][kkg 36][lane 64][8]
  int cb = blockIdx.x;                    // 0..3
  int rb = blockIdx.y;                    // 0..63
  int tid = threadIdx.x;
  int w = tid >> 6, lane = tid & 63;
  int rs = lane & 15, kg = lane >> 4;

  // stage B: contiguous 73728-u16 slice of W1f for col16 in [cb*4, cb*4+4)
  {
    const u16* src = Wf + (size_t)cb * 73728;
#pragma unroll
    for (int i = 0; i < 36; ++i) {
      int o = (i * 256 + tid) * 8;
      *(s16x8*)(Bs + o) = *(const s16x8*)(src + o);
    }
  }
  __syncthreads();

  int rend = min(rb * 784 + 784, NN);
  for (int cst = rb * 784 + w * 16; cst < rend; cst += 64) {
    int rowA = min(cst + rs, NN - 1);
    // hoist all 36 A-fragments (32 colour + 4 self) — deep MLP
    s16x8 af[36];
#pragma unroll
    for (int kkg = 0; kkg < 32; ++kkg)
      af[kkg] = *(const s16x8*)(agg + ((size_t)(kkg >> 2) * NN + rowA) * DD +
                                (kkg & 3) * 32 + kg * 8);
#pragma unroll
    for (int kk = 0; kk < 4; ++kk)
      af[32 + kk] = *(const s16x8*)(xb + (size_t)rowA * DD + kk * 32 + kg * 8);

    f32x4 acc[4];
#pragma unroll
    for (int i = 0; i < 4; i++)
#pragma unroll
      for (int q = 0; q < 4; q++) acc[i][q] = 0.f;

#pragma unroll
    for (int kkg = 0; kkg < 36; ++kkg) {
#pragma unroll
      for (int fc = 0; fc < 4; ++fc) {
        s16x8 bfr = *(const s16x8*)(Bs + (fc * 36 + kkg) * 512 + lane * 8);
        acc[fc] = __builtin_amdgcn_mfma_f32_16x16x32_bf16(af[kkg], bfr, acc[fc], 0, 0, 0);
      }
    }

#pragma unroll
    for (int fc = 0; fc < 4; ++fc) {
      int col = cb * 64 + fc * 16 + rs;
      float bias = b1[col];
#pragma unroll
      for (int q = 0; q < 4; ++q) {
        float v = acc[fc][q] + bias;
        if (v < 0.f) v = 0.f;
        int rr = cst + kg * 4 + q;
        if (rr < NN) hb[(size_t)rr * HH + col] = f2bf(v);
      }
    }
  }
}

// ---------------- layer 2 multiply-first: weight-stationary LDS-B ----------

__global__ void __launch_bounds__(256, 3) k_gemm2g(
    const u16* __restrict__ hb, const u16* __restrict__ Wf,
    u16* __restrict__ g2) {
  __shared__ u16 Bs[24576];               // 48KB
  int cb = blockIdx.x;                    // 0..11
  int rb = blockIdx.y;                    // 0..195
  int tid = threadIdx.x;
  int w = tid >> 6, lane = tid & 63;
  int rs = lane & 15, kg = lane >> 4;
  int c16b = cb * 6;

  {
    const u16* src = Wf + (size_t)cb * 24576;
#pragma unroll
    for (int i = 0; i < 12; ++i) {
      int o = (i * 256 + tid) * 8;
      *(s16x8*)(Bs + o) = *(const s16x8*)(src + o);
    }
  }
  __syncthreads();

#pragma unroll
  for (int tt = 0; tt < 2; ++tt) {
    int t = w + tt * 4;                   // chunk index 0..7
    int r0 = rb * 256 + t * 32;
    int rowA[2];
#pragma unroll
    for (int rg = 0; rg < 2; ++rg) rowA[rg] = min(r0 + rg * 16 + rs, NN - 1);

    s16x8 af[2][8];
#pragma unroll
    for (int rg = 0; rg < 2; ++rg)
#pragma unroll
      for (int kk = 0; kk < 8; ++kk)
        af[rg][kk] = *(const s16x8*)(hb + (size_t)rowA[rg] * HH + kk * 32 + kg * 8);

    f32x4 acc[2][6];
#pragma unroll
    for (int rg = 0; rg < 2; ++rg)
#pragma unroll
      for (int i = 0; i < 6; i++)
#pragma unroll
        for (int q = 0; q < 4; q++) acc[rg][i][q] = 0.f;

#pragma unroll
    for (int kk = 0; kk < 8; ++kk) {
#pragma unroll
      for (int fc = 0; fc < 6; ++fc) {
        s16x8 bfr = *(const s16x8*)(Bs + ((fc * 8 + kk) * 64 + lane) * 8);
#pragma unroll
        for (int rg = 0; rg < 2; ++rg)
          acc[rg][fc] = __builtin_amdgcn_mfma_f32_16x16x32_bf16(af[rg][kk], bfr, acc[rg][fc], 0, 0, 0);
      }
    }

#pragma unroll
    for (int rg = 0; rg < 2; ++rg) {
#pragma unroll
      for (int q = 0; q < 4; ++q) {
        int rr = r0 + rg * 16 + kg * 4 + q;
        if (rr < NN) {
#pragma unroll
          for (int fc = 0; fc < 6; ++fc) {
            int col = (c16b + fc) * 16 + rs;
            g2[(size_t)rr * 1152 + col] = f2bf(acc[rg][fc][q]);
          }
        }
      }
    }
  }
}

// ---------------- layer 2 final: flattened gather-sum-sigmoid ----------------

__global__ void __launch_bounds__(256) k_final(
    const u16* __restrict__ g2, const float* __restrict__ b2,
    const int2* __restrict__ oc, const int* __restrict__ sv,
    float* __restrict__ out) {
  int item = blockIdx.x * 256 + threadIdx.x;
  if (item >= NN * 8) return;
  int dst = item >> 3, ch = item & 7;
  int eoff = ch * 16;

  int st, cn;
  {
    int2 a0 = oc[dst * CC];
    int2 a7 = oc[dst * CC + 7];
    st = a0.x;
    cn = a7.x + a7.y - a0.x;
  }

  float s[16];
  {
    const u16* sp = g2 + (size_t)dst * 1152 + 1024 + eoff;
    s16x8 lo = *(const s16x8*)sp;
    s16x8 hi = *(const s16x8*)(sp + 8);
#pragma unroll
    for (int q = 0; q < 8; q++) s[q] = b2[eoff + q] + bf2f(lo[q]);
#pragma unroll
    for (int q = 0; q < 8; q++) s[q + 8] = b2[eoff + 8 + q] + bf2f(hi[q]);
  }

  for (int j = 0; j < cn; j += 4) {
    int pofs[4];
#pragma unroll
    for (int t = 0; t < 4; t++) {
      int jj = j + t;
      if (jj < cn) {
        int v = sv[st + jj];
        pofs[t] = (v >> 3) * 1152 + (v & 7) * 128;
      } else {
        pofs[t] = -1;
      }
    }
#pragma unroll
    for (int t = 0; t < 4; t++) {
      if (pofs[t] >= 0) {
        const u16* pp = g2 + pofs[t] + eoff;
        s16x8 lo = *(const s16x8*)pp;
        s16x8 hi = *(const s16x8*)(pp + 8);
#pragma unroll
        for (int q = 0; q < 8; q++) s[q] += bf2f(lo[q]);
#pragma unroll
        for (int q = 0; q < 8; q++) s[q + 8] += bf2f(hi[q]);
      }
    }
  }
  float* op = out + (size_t)dst * DD + eoff;
#pragma unroll
  for (int q = 0; q < 16; q++) op[q] = 1.f / (1.f + expf(10.f - s[q]));
}

// ---------------- launch ----------------

extern "C" void kernel_launch(void* const* d_in, const int* in_sizes, int n_in,
                              void* d_out, int out_size, void* d_ws, size_t ws_size,
                              hipStream_t stream) {
  const float* x   = (const float*)d_in[0];
  const int*   ei  = (const int*)d_in[1];
  const int*   ec  = (const int*)d_in[2];
  const float* Ws1 = (const float*)d_in[3];
  const float* b1  = (const float*)d_in[4];
  const float* Ws2 = (const float*)d_in[5];
  const float* b2  = (const float*)d_in[6];
  const float* Wc1 = (const float*)d_in[7];
  const float* Wc2 = (const float*)d_in[8];
  float* out = (float*)d_out;

  char* p = (char*)d_ws;
  // g2 [N,1152] bf16 (115.2MB) aliases agg1 (102.4MB) + xb (12.8MB).
  u16*  g2     = (u16*)p;
  u16*  agg1   = (u16*)p;                         // [C*N,128] bf16
  u16*  xb     = (u16*)(p + 102400000);           // [N,128] bf16
  u16*  hb     = (u16*)(p + 115200000);           // [N,256] bf16
  u16*  W1f    = (u16*)(p + 140800000);           // frag-major
  u16*  W2f    = (u16*)(p + 141389824);           // frag-major
  int2* oc     = (int2*)(p + 141979648);          // [N*C] {off,cnt}
  int*  sv     = (int*)(p + 145179648);           // [E] src*8+c
  int*  counts = (int*)(p + 148379648);           // [N*C]
  int*  gcount = (int*)(p + 149979648);
  int*  cursor = (int*)(p + 149979904);           // [N*C]

  hipMemsetAsync(counts, 0, 1600256, stream);     // counts + gcount

  k_castx<<<25000, 256, 0, stream>>>(x, xb);
  k_wt1f<<<1152, 256, 0, stream>>>(Wc1, Ws1, W1f);
  k_wt2f<<<1152, 256, 0, stream>>>(Wc2, Ws2, W2f);

  k_hist<<<3125, 256, 0, stream>>>(ei, ec, counts);
  k_offsets<<<1563, 256, 0, stream>>>(counts, oc, cursor, gcount);
  k_fill<<<3125, 256, 0, stream>>>(ei, ec, cursor, sv);

  k_agg1<<<3125, 256, 0, stream>>>(xb, oc, sv, agg1);
  k_gemm1s<<<dim3(4, 64), 256, 0, stream>>>(xb, agg1, W1f, b1, hb);
  k_gemm2g<<<dim3(12, 196), 256, 0, stream>>>(hb, W2f, g2);
  k_final<<<1563, 256, 0, stream>>>(g2, b2, oc, sv, out);
}

// Round 20
// 344.383 us; speedup vs baseline: 1.4643x; 1.4643x over previous
//
#include <hip/hip_runtime.h>

// GNN: 2-layer edge-coloured conv on MI355X.
// Round 20 (= round 19 resubmit after infra failure): k_gemm1s = r17 shape +
// software pipeline: double-buffered 32KB LDS-B, A prefetched one phase
// ahead, ONE barrier/phase, fully unrolled 9-phase loop with ping-ponged
// named A-register arrays. Everything else = round 17 (passed, 341us).

#define NN 50000
#define EE 800000
#define DD 128
#define HH 256
#define CC 8
#define K1 1152   // C*D + D

typedef unsigned short u16;
typedef __attribute__((ext_vector_type(8))) short s16x8;
typedef __attribute__((ext_vector_type(4))) float f32x4;

__device__ __forceinline__ float bf2f(short u) {
  return __uint_as_float(((unsigned)(u16)u) << 16);
}
__device__ __forceinline__ u16 f2bf(float f) {
  unsigned u = __float_as_uint(f);
  u = (u + 0x7FFFu + ((u >> 16) & 1u)) >> 16;   // RNE
  return (u16)u;
}

// ---------------- prep ----------------

__global__ void k_castx(const float* __restrict__ x, u16* __restrict__ xb) {
  int i = blockIdx.x * 256 + threadIdx.x;
  if (i < NN * DD) xb[i] = f2bf(x[i]);
}

// W1f fragment-major: idx = (((col16*36 + kk)*4 + kg)*16 + rs)*8 + e
__global__ void k_wt1f(const float* __restrict__ Wc1, const float* __restrict__ Ws1,
                       u16* __restrict__ W) {
  int i = blockIdx.x * 256 + threadIdx.x;
  if (i >= 294912) return;
  int e = i & 7;
  int t = i >> 3;
  int rs = t & 15; t >>= 4;
  int kg = t & 3;  t >>= 2;
  int kk = t % 36;
  int col16 = t / 36;
  int col = col16 * 16 + rs;
  int k = kk * 32 + kg * 8 + e;
  float v = (k < CC * DD) ? Wc1[(k >> 7) * (HH * DD) + col * DD + (k & 127)]
                          : Ws1[col * DD + (k - CC * DD)];
  W[i] = f2bf(v);
}

// W2f fragment-major: idx = (((col16*8 + kk)*4 + kg)*16 + rs)*8 + e
__global__ void k_wt2f(const float* __restrict__ Wc2, const float* __restrict__ Ws2,
                       u16* __restrict__ W) {
  int i = blockIdx.x * 256 + threadIdx.x;
  if (i >= 294912) return;
  int e = i & 7;
  int t = i >> 3;
  int rs = t & 15; t >>= 4;
  int kg = t & 3;  t >>= 2;
  int kk = t & 7;
  int col16 = t >> 3;
  int oc = col16 * 16 + rs;
  int c = oc >> 7, o = oc & 127;
  int k = kk * 32 + kg * 8 + e;
  float v = (c < CC) ? Wc2[c * (DD * HH) + o * HH + k] : Ws2[o * HH + k];
  W[i] = f2bf(v);
}

// ---------------- CSR build over seg = dst*8 + c ----------------

__global__ void k_hist(const int* __restrict__ ei, const int* __restrict__ ec,
                       int* __restrict__ counts) {
  int e = blockIdx.x * 256 + threadIdx.x;
  if (e < EE) {
    int dst = ei[EE + e];
    int c = ec[e];
    atomicAdd(&counts[dst * CC + c], 1);
  }
}

__global__ void k_offsets(const int* __restrict__ counts, int2* __restrict__ oc,
                          int* __restrict__ cursor, int* __restrict__ gcount) {
  __shared__ int lds[256];
  __shared__ int basesh;
  int tid = threadIdx.x;
  int i = blockIdx.x * 256 + tid;
  int c = (i < CC * NN) ? counts[i] : 0;
  lds[tid] = c;
  __syncthreads();
  int v = c;
  for (int s = 1; s < 256; s <<= 1) {
    int t = (tid >= s) ? lds[tid - s] : 0;
    __syncthreads();
    v += t;
    lds[tid] = v;
    __syncthreads();
  }
  if (tid == 255) basesh = atomicAdd(gcount, v);
  __syncthreads();
  int excl = basesh + v - c;
  if (i < CC * NN) {
    oc[i] = make_int2(excl, c);
    cursor[i] = excl;
  }
}

// slot value packs src and colour: sv = src*8 + c
__global__ void k_fill(const int* __restrict__ ei, const int* __restrict__ ec,
                       int* __restrict__ cursor, int* __restrict__ sv) {
  int e = blockIdx.x * 256 + threadIdx.x;
  if (e < EE) {
    int src = ei[e];
    int dst = ei[EE + e];
    int c = ec[e];
    int slot = atomicAdd(&cursor[dst * CC + c], 1);
    sv[slot] = src * 8 + c;
  }
}

// ---------------- layer 1: balanced pure gather ----------------

__global__ void __launch_bounds__(256) k_agg1(
    const u16* __restrict__ xb, const int2* __restrict__ oc,
    const int* __restrict__ sv, u16* __restrict__ agg) {
  int item = blockIdx.x * 256 + threadIdx.x;
  int dst = item >> 4, ch = item & 15;
  int eoff = ch * 8;
#pragma unroll
  for (int c = 0; c < CC; ++c) {
    int2 se = oc[dst * CC + c];
    float s[8];
#pragma unroll
    for (int q = 0; q < 8; q++) s[q] = 0.f;
    int j = 0;
    for (; j + 1 < se.y; j += 2) {
      int s0 = sv[se.x + j] >> 3;
      int s1 = sv[se.x + j + 1] >> 3;
      s16x8 v0 = *(const s16x8*)(xb + (size_t)s0 * DD + eoff);
      s16x8 v1 = *(const s16x8*)(xb + (size_t)s1 * DD + eoff);
#pragma unroll
      for (int q = 0; q < 8; q++) s[q] += bf2f(v0[q]) + bf2f(v1[q]);
    }
    if (j < se.y) {
      int s0 = sv[se.x + j] >> 3;
      s16x8 v0 = *(const s16x8*)(xb + (size_t)s0 * DD + eoff);
#pragma unroll
      for (int q = 0; q < 8; q++) s[q] += bf2f(v0[q]);
    }
    s16x8 r;
#pragma unroll
    for (int q = 0; q < 8; q++) r[q] = (short)f2bf(s[q]);
    *(s16x8*)(agg + ((size_t)c * NN + dst) * DD + eoff) = r;
  }
}

// ---------------- layer 1 dense: pipelined per-colour LDS-B ----------------
// Grid (2 ch, 391 rb). Block 128x128, 4 waves x 32 rows. Double-buffered B
// (2x32KB), A prefetched one phase ahead, one barrier per phase.

#define LOADA(af, p) do {                                                      \
  if ((p) < CC) {                                                              \
    _Pragma("unroll") for (int rg = 0; rg < 2; ++rg)                           \
    _Pragma("unroll") for (int kk = 0; kk < 4; ++kk)                           \
      af[rg][kk] = *(const s16x8*)(agg + ((size_t)(p) * NN + rowA[rg]) * DD +  \
                                   kk * 32 + kg * 8);                          \
  } else {                                                                     \
    _Pragma("unroll") for (int rg = 0; rg < 2; ++rg)                           \
    _Pragma("unroll") for (int kk = 0; kk < 4; ++kk)                           \
      af[rg][kk] = *(const s16x8*)(xb + (size_t)rowA[rg] * DD +                \
                                   kk * 32 + kg * 8);                          \
  } } while (0)

#define STAGE1(p, buf) do {                                                    \
  _Pragma("unroll") for (int i = 0; i < 8; ++i) {                              \
    int li = i * 256 + tid;                                                    \
    int fc = li >> 8; int u = li & 255; int kkl = u >> 6; int j = u & 63;      \
    *(s16x8*)(Bs + (buf) * 16384 + (fc * 4 + kkl) * 512 + j * 8) =             \
      *(const s16x8*)(Wf + (size_t)((ch * 8 + fc) * 36 + (p) * 4 + kkl) * 512  \
                      + j * 8);                                                \
  } } while (0)

#define MFMAPH(af, buf) do {                                                   \
  _Pragma("unroll") for (int kk = 0; kk < 4; ++kk)                             \
  _Pragma("unroll") for (int fc = 0; fc < 8; ++fc) {                           \
    s16x8 bfr = *(const s16x8*)(Bs + (buf) * 16384 + (fc * 4 + kk) * 512 +     \
                                lane * 8);                                     \
    _Pragma("unroll") for (int rg = 0; rg < 2; ++rg)                           \
      acc[rg][fc] = __builtin_amdgcn_mfma_f32_16x16x32_bf16(af[rg][kk], bfr,   \
                                                            acc[rg][fc], 0, 0, 0); \
  } } while (0)

__global__ void __launch_bounds__(256, 1) k_gemm1s(
    const u16* __restrict__ xb, const u16* __restrict__ agg,
    const u16* __restrict__ Wf, const float* __restrict__ b1,
    u16* __restrict__ hb) {
  __shared__ u16 Bs[32768];               // 2 x 32KB
  int ch = blockIdx.x;                    // 0..1
  int rb = blockIdx.y;                    // 0..390
  int tid = threadIdx.x;
  int w = tid >> 6, lane = tid & 63;
  int rs = lane & 15, kg = lane >> 4;
  int r0 = rb * 128 + w * 32;

  int rowA[2];
#pragma unroll
  for (int rg = 0; rg < 2; ++rg) rowA[rg] = min(r0 + rg * 16 + rs, NN - 1);

  f32x4 acc[2][8];
#pragma unroll
  for (int rg = 0; rg < 2; ++rg)
#pragma unroll
    for (int i = 0; i < 8; i++)
#pragma unroll
      for (int q = 0; q < 4; q++) acc[rg][i][q] = 0.f;

  s16x8 afA[2][4], afB[2][4];
  STAGE1(0, 0);
  LOADA(afA, 0);
  __syncthreads();

#pragma unroll
  for (int ph = 0; ph < 9; ++ph) {        // 8 colours + self
    const int pb = ph & 1;
    if (ph < 8) {
      STAGE1(ph + 1, pb ^ 1);
      if (pb == 0) { LOADA(afB, ph + 1); } else { LOADA(afA, ph + 1); }
    }
    if (pb == 0) { MFMAPH(afA, 0); } else { MFMAPH(afB, 1); }
    __syncthreads();
  }

#pragma unroll
  for (int fc = 0; fc < 8; ++fc) {
    int col = ch * 128 + fc * 16 + rs;
    float bias = b1[col];
#pragma unroll
    for (int rg = 0; rg < 2; ++rg) {
#pragma unroll
      for (int q = 0; q < 4; ++q) {
        float v = acc[rg][fc][q] + bias;
        if (v < 0.f) v = 0.f;
        int rr = r0 + rg * 16 + kg * 4 + q;
        if (rr < NN) hb[(size_t)rr * HH + col] = f2bf(v);
      }
    }
  }
}

// ---------------- layer 2 multiply-first: weight-stationary LDS-B ----------

__global__ void __launch_bounds__(256, 3) k_gemm2g(
    const u16* __restrict__ hb, const u16* __restrict__ Wf,
    u16* __restrict__ g2) {
  __shared__ u16 Bs[24576];               // 48KB
  int cb = blockIdx.x;                    // 0..11
  int rb = blockIdx.y;                    // 0..195
  int tid = threadIdx.x;
  int w = tid >> 6, lane = tid & 63;
  int rs = lane & 15, kg = lane >> 4;
  int c16b = cb * 6;

  {
    const u16* src = Wf + (size_t)cb * 24576;
#pragma unroll
    for (int i = 0; i < 12; ++i) {
      int o = (i * 256 + tid) * 8;
      *(s16x8*)(Bs + o) = *(const s16x8*)(src + o);
    }
  }
  __syncthreads();

#pragma unroll
  for (int tt = 0; tt < 2; ++tt) {
    int t = w + tt * 4;                   // chunk index 0..7
    int r0 = rb * 256 + t * 32;
    int rowA[2];
#pragma unroll
    for (int rg = 0; rg < 2; ++rg) rowA[rg] = min(r0 + rg * 16 + rs, NN - 1);

    s16x8 af[2][8];
#pragma unroll
    for (int rg = 0; rg < 2; ++rg)
#pragma unroll
      for (int kk = 0; kk < 8; ++kk)
        af[rg][kk] = *(const s16x8*)(hb + (size_t)rowA[rg] * HH + kk * 32 + kg * 8);

    f32x4 acc[2][6];
#pragma unroll
    for (int rg = 0; rg < 2; ++rg)
#pragma unroll
      for (int i = 0; i < 6; i++)
#pragma unroll
        for (int q = 0; q < 4; q++) acc[rg][i][q] = 0.f;

#pragma unroll
    for (int kk = 0; kk < 8; ++kk) {
#pragma unroll
      for (int fc = 0; fc < 6; ++fc) {
        s16x8 bfr = *(const s16x8*)(Bs + ((fc * 8 + kk) * 64 + lane) * 8);
#pragma unroll
        for (int rg = 0; rg < 2; ++rg)
          acc[rg][fc] = __builtin_amdgcn_mfma_f32_16x16x32_bf16(af[rg][kk], bfr, acc[rg][fc], 0, 0, 0);
      }
    }

#pragma unroll
    for (int rg = 0; rg < 2; ++rg) {
#pragma unroll
      for (int q = 0; q < 4; ++q) {
        int rr = r0 + rg * 16 + kg * 4 + q;
        if (rr < NN) {
#pragma unroll
          for (int fc = 0; fc < 6; ++fc) {
            int col = (c16b + fc) * 16 + rs;
            g2[(size_t)rr * 1152 + col] = f2bf(acc[rg][fc][q]);
          }
        }
      }
    }
  }
}

// ---------------- layer 2 final: flattened gather-sum-sigmoid ----------------

__global__ void __launch_bounds__(256) k_final(
    const u16* __restrict__ g2, const float* __restrict__ b2,
    const int2* __restrict__ oc, const int* __restrict__ sv,
    float* __restrict__ out) {
  int item = blockIdx.x * 256 + threadIdx.x;
  if (item >= NN * 8) return;
  int dst = item >> 3, ch = item & 7;
  int eoff = ch * 16;

  int st, cn;
  {
    int2 a0 = oc[dst * CC];
    int2 a7 = oc[dst * CC + 7];
    st = a0.x;
    cn = a7.x + a7.y - a0.x;
  }

  float s[16];
  {
    const u16* sp = g2 + (size_t)dst * 1152 + 1024 + eoff;
    s16x8 lo = *(const s16x8*)sp;
    s16x8 hi = *(const s16x8*)(sp + 8);
#pragma unroll
    for (int q = 0; q < 8; q++) s[q] = b2[eoff + q] + bf2f(lo[q]);
#pragma unroll
    for (int q = 0; q < 8; q++) s[q + 8] = b2[eoff + 8 + q] + bf2f(hi[q]);
  }

  for (int j = 0; j < cn; j += 4) {
    int pofs[4];
#pragma unroll
    for (int t = 0; t < 4; t++) {
      int jj = j + t;
      if (jj < cn) {
        int v = sv[st + jj];
        pofs[t] = (v >> 3) * 1152 + (v & 7) * 128;
      } else {
        pofs[t] = -1;
      }
    }
#pragma unroll
    for (int t = 0; t < 4; t++) {
      if (pofs[t] >= 0) {
        const u16* pp = g2 + pofs[t] + eoff;
        s16x8 lo = *(const s16x8*)pp;
        s16x8 hi = *(const s16x8*)(pp + 8);
#pragma unroll
        for (int q = 0; q < 8; q++) s[q] += bf2f(lo[q]);
#pragma unroll
        for (int q = 0; q < 8; q++) s[q + 8] += bf2f(hi[q]);
      }
    }
  }
  float* op = out + (size_t)dst * DD + eoff;
#pragma unroll
  for (int q = 0; q < 16; q++) op[q] = 1.f / (1.f + expf(10.f - s[q]));
}

// ---------------- launch ----------------

extern "C" void kernel_launch(void* const* d_in, const int* in_sizes, int n_in,
                              void* d_out, int out_size, void* d_ws, size_t ws_size,
                              hipStream_t stream) {
  const float* x   = (const float*)d_in[0];
  const int*   ei  = (const int*)d_in[1];
  const int*   ec  = (const int*)d_in[2];
  const float* Ws1 = (const float*)d_in[3];
  const float* b1  = (const float*)d_in[4];
  const float* Ws2 = (const float*)d_in[5];
  const float* b2  = (const float*)d_in[6];
  const float* Wc1 = (const float*)d_in[7];
  const float* Wc2 = (const float*)d_in[8];
  float* out = (float*)d_out;

  char* p = (char*)d_ws;
  // g2 [N,1152] bf16 (115.2MB) aliases agg1 (102.4MB) + xb (12.8MB).
  u16*  g2     = (u16*)p;
  u16*  agg1   = (u16*)p;                         // [C*N,128] bf16
  u16*  xb     = (u16*)(p + 102400000);           // [N,128] bf16
  u16*  hb     = (u16*)(p + 115200000);           // [N,256] bf16
  u16*  W1f    = (u16*)(p + 140800000);           // frag-major
  u16*  W2f    = (u16*)(p + 141389824);           // frag-major
  int2* oc     = (int2*)(p + 141979648);          // [N*C] {off,cnt}
  int*  sv     = (int*)(p + 145179648);           // [E] src*8+c
  int*  counts = (int*)(p + 148379648);           // [N*C]
  int*  gcount = (int*)(p + 149979648);
  int*  cursor = (int*)(p + 149979904);           // [N*C]

  hipMemsetAsync(counts, 0, 1600256, stream);     // counts + gcount

  k_castx<<<25000, 256, 0, stream>>>(x, xb);
  k_wt1f<<<1152, 256, 0, stream>>>(Wc1, Ws1, W1f);
  k_wt2f<<<1152, 256, 0, stream>>>(Wc2, Ws2, W2f);

  k_hist<<<3125, 256, 0, stream>>>(ei, ec, counts);
  k_offsets<<<1563, 256, 0, stream>>>(counts, oc, cursor, gcount);
  k_fill<<<3125, 256, 0, stream>>>(ei, ec, cursor, sv);

  k_agg1<<<3125, 256, 0, stream>>>(xb, oc, sv, agg1);
  k_gemm1s<<<dim3(2, 391), 256, 0, stream>>>(xb, agg1, W1f, b1, hb);
  k_gemm2g<<<dim3(12, 196), 256, 0, stream>>>(hb, W2f, g2);
  k_final<<<1563, 256, 0, stream>>>(g2, b2, oc, sv, out);
}